// Round 1
// baseline (180.494 us; speedup 1.0000x reference)
//
#include <hip/hip_runtime.h>

// Problem constants (from reference)
#define BATCH 16
#define NSEG 32
#define HH 512
#define WW 1024
#define HW (HH * WW)                 // 524288 pixels per batch
#define MIN_PIX 50.0f

// Kernel 1 config
#define THREADS 256
#define CHUNKS 64                    // blocks per batch
#define PIX_PER_BLOCK (HW / CHUNKS)  // 8192
#define VEC 4
#define ITERS (PIX_PER_BLOCK / (THREADS * VEC))  // 8
#define NREP 8                       // LDS replica count (power of 2)

// Accumulator layout in d_ws: acc[b][s][4] floats, comp: 0=cnt 1=su 2=sv 3=s2
#define ACC_FLOATS (BATCH * NSEG * 4)

__global__ __launch_bounds__(THREADS) void ovl_accum(
    const float* __restrict__ flow,   // [B, 2, H, W]
    const int* __restrict__ masks,    // [B, H, W]
    float* __restrict__ acc)          // [B, S, 4], pre-zeroed
{
    __shared__ float sm[4][NREP][NSEG];  // 4 KiB

    const int tid = threadIdx.x;
    // zero LDS
    for (int i = tid; i < 4 * NREP * NSEG; i += THREADS)
        ((float*)sm)[i] = 0.0f;
    __syncthreads();

    const int b = blockIdx.y;
    const int chunk = blockIdx.x;
    const float* __restrict__ u_base = flow + (size_t)b * 2 * HW;
    const float* __restrict__ v_base = u_base + HW;
    const int*   __restrict__ m_base = masks + (size_t)b * HW;
    const int p0 = chunk * PIX_PER_BLOCK;
    const int rep = tid & (NREP - 1);

    #pragma unroll
    for (int it = 0; it < ITERS; ++it) {
        const int p = p0 + (it * THREADS + tid) * VEC;
        const int4   m4 = *(const int4*)(m_base + p);
        const float4 u4 = *(const float4*)(u_base + p);
        const float4 v4 = *(const float4*)(v_base + p);
        const int   ms[4] = {m4.x, m4.y, m4.z, m4.w};
        const float us[4] = {u4.x, u4.y, u4.z, u4.w};
        const float vs[4] = {v4.x, v4.y, v4.z, v4.w};
        #pragma unroll
        for (int j = 0; j < 4; ++j) {
            const int s = ms[j] & (NSEG - 1);
            const float u = us[j];
            const float v = vs[j];
            atomicAdd(&sm[0][rep][s], 1.0f);
            atomicAdd(&sm[1][rep][s], u);
            atomicAdd(&sm[2][rep][s], v);
            atomicAdd(&sm[3][rep][s], u * u + v * v);
        }
    }
    __syncthreads();

    // Reduce replicas, one (comp, seg) pair per thread (128 of them), then
    // one global fp32 atomic each.
    if (tid < 4 * NSEG) {
        const int comp = tid >> 5;   // 0..3
        const int s = tid & (NSEG - 1);
        float sum = 0.0f;
        #pragma unroll
        for (int r = 0; r < NREP; ++r) sum += sm[comp][r][s];
        atomicAdd(&acc[((size_t)b * NSEG + s) * 4 + comp], sum);
    }
}

__global__ __launch_bounds__(BATCH * NSEG) void ovl_finalize(
    const float* __restrict__ acc,   // [B*S, 4]
    float* __restrict__ out)         // scalar
{
    const int tid = threadIdx.x;     // 0..511, one per global segment id
    const float cnt = acc[tid * 4 + 0];
    const float su  = acc[tid * 4 + 1];
    const float sv  = acc[tid * 4 + 2];
    const float s2  = acc[tid * 4 + 3];

    const bool is_bg = (tid & (NSEG - 1)) == 0;
    const bool valid = (cnt >= MIN_PIX) && !is_bg;

    const float safe_cnt = fmaxf(cnt, 1.0f);
    const float denom = fmaxf(cnt - 1.0f, 1.0f);
    const float var_sum = (s2 - (su * su + sv * sv) / safe_cnt) / denom;

    float t = valid ? var_sum : 0.0f;
    float n = valid ? 1.0f : 0.0f;

    // wave (64-lane) shuffle reduction
    #pragma unroll
    for (int off = 32; off >= 1; off >>= 1) {
        t += __shfl_down(t, off, 64);
        n += __shfl_down(n, off, 64);
    }

    __shared__ float st[8], sn[8];   // 512 threads = 8 waves
    const int wave = tid >> 6;
    const int lane = tid & 63;
    if (lane == 0) { st[wave] = t; sn[wave] = n; }
    __syncthreads();

    if (tid == 0) {
        float tot = 0.0f, ntot = 0.0f;
        #pragma unroll
        for (int w = 0; w < 8; ++w) { tot += st[w]; ntot += sn[w]; }
        out[0] = (ntot > 0.0f) ? (tot / fmaxf(ntot, 1.0f)) : 0.0f;
    }
}

extern "C" void kernel_launch(void* const* d_in, const int* in_sizes, int n_in,
                              void* d_out, int out_size, void* d_ws, size_t ws_size,
                              hipStream_t stream) {
    const float* flow = (const float*)d_in[0];
    const int* masks  = (const int*)d_in[1];
    float* out = (float*)d_out;
    float* acc = (float*)d_ws;

    hipMemsetAsync(acc, 0, ACC_FLOATS * sizeof(float), stream);

    dim3 grid(CHUNKS, BATCH);
    ovl_accum<<<grid, THREADS, 0, stream>>>(flow, masks, acc);
    ovl_finalize<<<1, BATCH * NSEG, 0, stream>>>(acc, out);
}

// Round 2
// 180.245 us; speedup vs baseline: 1.0014x; 1.0014x over previous
//
#include <hip/hip_runtime.h>

// Problem constants (from reference)
#define BATCH 16
#define NSEG 32
#define HH 512
#define WW 1024
#define HW (HH * WW)                 // 524288 pixels per batch
#define MIN_PIX 50.0f

// Kernel 1 config
#define THREADS 256
#define CHUNKS 64                    // blocks per batch
#define PIX_PER_BLOCK (HW / CHUNKS)  // 8192
#define VEC 4
#define ITERS (PIX_PER_BLOCK / (THREADS * VEC))  // 8
#define NREP 16                      // LDS replica count (power of 2)

// Accumulator layout in d_ws: acc[b][s][4] floats, comp: 0=cnt 1=su 2=sv 3=s2
#define ACC_FLOATS (BATCH * NSEG * 4)

__global__ __launch_bounds__(THREADS) void ovl_accum(
    const float* __restrict__ flow,   // [B, 2, H, W]
    const int* __restrict__ masks,    // [B, H, W]
    float* __restrict__ acc)          // [B, S, 4], pre-zeroed
{
    // sm[comp][rep][seg]: word index = c*512 + r*32 + s  -> bank = s
    __shared__ float sm[4][NREP][NSEG];  // 8 KiB

    const int tid = threadIdx.x;
    // zero LDS
    #pragma unroll
    for (int i = tid; i < 4 * NREP * NSEG; i += THREADS)
        ((float*)sm)[i] = 0.0f;
    __syncthreads();

    const int b = blockIdx.y;
    const int chunk = blockIdx.x;
    const float* __restrict__ u_base = flow + (size_t)b * 2 * HW;
    const float* __restrict__ v_base = u_base + HW;
    const int*   __restrict__ m_base = masks + (size_t)b * HW;
    const int p0 = chunk * PIX_PER_BLOCK;
    const int rep = tid & (NREP - 1);

    #pragma unroll
    for (int it = 0; it < ITERS; ++it) {
        const int p = p0 + (it * THREADS + tid) * VEC;
        const int4   m4 = *(const int4*)(m_base + p);
        const float4 u4 = *(const float4*)(u_base + p);
        const float4 v4 = *(const float4*)(v_base + p);
        const int   ms[4] = {m4.x, m4.y, m4.z, m4.w};
        const float us[4] = {u4.x, u4.y, u4.z, u4.w};
        const float vs[4] = {v4.x, v4.y, v4.z, v4.w};
        #pragma unroll
        for (int j = 0; j < 4; ++j) {
            const int s = ms[j] & (NSEG - 1);
            const float u = us[j];
            const float v = vs[j];
            // Native ds_add_f32 (no return) — fire-and-forget, no CAS loop.
            unsafeAtomicAdd(&sm[0][rep][s], 1.0f);
            unsafeAtomicAdd(&sm[1][rep][s], u);
            unsafeAtomicAdd(&sm[2][rep][s], v);
            unsafeAtomicAdd(&sm[3][rep][s], u * u + v * v);
        }
    }
    __syncthreads();

    // Reduce replicas, one (comp, seg) pair per thread (128 of them), then
    // one native global fp32 atomic each (2048 distinct addresses total).
    if (tid < 4 * NSEG) {
        const int comp = tid >> 5;   // 0..3
        const int s = tid & (NSEG - 1);
        float sum = 0.0f;
        #pragma unroll
        for (int r = 0; r < NREP; ++r) sum += sm[comp][r][s];
        unsafeAtomicAdd(&acc[((size_t)b * NSEG + s) * 4 + comp], sum);
    }
}

__global__ __launch_bounds__(BATCH * NSEG) void ovl_finalize(
    const float* __restrict__ acc,   // [B*S, 4]
    float* __restrict__ out)         // scalar
{
    const int tid = threadIdx.x;     // 0..511, one per global segment id
    const float cnt = acc[tid * 4 + 0];
    const float su  = acc[tid * 4 + 1];
    const float sv  = acc[tid * 4 + 2];
    const float s2  = acc[tid * 4 + 3];

    const bool is_bg = (tid & (NSEG - 1)) == 0;
    const bool valid = (cnt >= MIN_PIX) && !is_bg;

    const float safe_cnt = fmaxf(cnt, 1.0f);
    const float denom = fmaxf(cnt - 1.0f, 1.0f);
    const float var_sum = (s2 - (su * su + sv * sv) / safe_cnt) / denom;

    float t = valid ? var_sum : 0.0f;
    float n = valid ? 1.0f : 0.0f;

    // wave (64-lane) shuffle reduction
    #pragma unroll
    for (int off = 32; off >= 1; off >>= 1) {
        t += __shfl_down(t, off, 64);
        n += __shfl_down(n, off, 64);
    }

    __shared__ float st[8], sn[8];   // 512 threads = 8 waves
    const int wave = tid >> 6;
    const int lane = tid & 63;
    if (lane == 0) { st[wave] = t; sn[wave] = n; }
    __syncthreads();

    if (tid == 0) {
        float tot = 0.0f, ntot = 0.0f;
        #pragma unroll
        for (int w = 0; w < 8; ++w) { tot += st[w]; ntot += sn[w]; }
        out[0] = (ntot > 0.0f) ? (tot / fmaxf(ntot, 1.0f)) : 0.0f;
    }
}

extern "C" void kernel_launch(void* const* d_in, const int* in_sizes, int n_in,
                              void* d_out, int out_size, void* d_ws, size_t ws_size,
                              hipStream_t stream) {
    const float* flow = (const float*)d_in[0];
    const int* masks  = (const int*)d_in[1];
    float* out = (float*)d_out;
    float* acc = (float*)d_ws;

    hipMemsetAsync(acc, 0, ACC_FLOATS * sizeof(float), stream);

    dim3 grid(CHUNKS, BATCH);
    ovl_accum<<<grid, THREADS, 0, stream>>>(flow, masks, acc);
    ovl_finalize<<<1, BATCH * NSEG, 0, stream>>>(acc, out);
}

// Round 3
// 31.101 us; speedup vs baseline: 5.8036x; 5.7955x over previous
//
#include <hip/hip_runtime.h>

// Problem constants (from reference)
#define BATCH 16
#define NSEG 32
#define HW (512 * 1024)              // 524288 pixels per batch
#define MIN_PIX 50.0f

// Kernel 1 config: 64-thread (1-wave) blocks, per-thread privatized LDS bins.
#define THREADS 64
#define CHUNKS 64                    // blocks per batch
#define PIX_PER_BLOCK (HW / CHUNKS)  // 8192
#define VEC 4
#define ITERS (PIX_PER_BLOCK / (THREADS * VEC))  // 32

// Accumulator layout in d_ws: acc[b][s][4] floats, comp: 0=cnt 1=su 2=sv 3=s2
#define ACC_FLOATS (BATCH * NSEG * 4)

__global__ __launch_bounds__(THREADS) void ovl_accum(
    const float* __restrict__ flow,   // [B, 2, H, W]
    const int* __restrict__ masks,    // [B, H, W]
    float* __restrict__ acc)          // [B, S, 4], pre-zeroed
{
    // Per-thread private bins: no atomics, unique address per lane.
    // word addr = tid*128 + s*4 + comp -> start bank = (s*4)&31, ~2 lanes/bank.
    __shared__ float4 bins[THREADS][NSEG];   // 32 KiB

    const int tid = threadIdx.x;
    #pragma unroll
    for (int i = 0; i < NSEG; ++i)
        bins[tid][i] = make_float4(0.0f, 0.0f, 0.0f, 0.0f);
    __syncthreads();

    const int b = blockIdx.y;
    const int chunk = blockIdx.x;
    const float* __restrict__ u_base = flow + (size_t)b * 2 * HW;
    const float* __restrict__ v_base = u_base + HW;
    const int*   __restrict__ m_base = masks + (size_t)b * HW;
    const int p0 = chunk * PIX_PER_BLOCK;

#define LOADP(S, IT) { const int p = p0 + ((IT) * THREADS + tid) * VEC;        \
        m##S = *(const int4*)(m_base + p);                                    \
        u##S = *(const float4*)(u_base + p);                                  \
        v##S = *(const float4*)(v_base + p); }

#define PROC1(mm, uu, vv) { const int s = (mm) & (NSEG - 1);                   \
        float4 cur = bins[tid][s];                                            \
        cur.x += 1.0f; cur.y += (uu); cur.z += (vv);                          \
        cur.w += (uu) * (uu) + (vv) * (vv);                                   \
        bins[tid][s] = cur; }

#define PROCP(S) { PROC1(m##S.x, u##S.x, v##S.x) PROC1(m##S.y, u##S.y, v##S.y) \
        PROC1(m##S.z, u##S.z, v##S.z) PROC1(m##S.w, u##S.w, v##S.w) }

    int4 mA, mB; float4 uA, vA, uB, vB;
    LOADP(A, 0)
    LOADP(B, 1)
    #pragma unroll
    for (int it = 0; it < ITERS; it += 2) {
        PROCP(A)
        if (it + 2 < ITERS) LOADP(A, it + 2)
        PROCP(B)
        if (it + 3 < ITERS) LOADP(B, it + 3)
    }
    __syncthreads();

    // Reduce the 64 private rows -> one native global fp32 atomic per
    // (seg,comp) pair (128 per block, 2048 distinct addresses total).
    const float* smf = (const float*)bins;   // [THREADS][NSEG*4]
    #pragma unroll
    for (int pair = tid; pair < NSEG * 4; pair += THREADS) {
        float sum = 0.0f;
        #pragma unroll
        for (int j = 0; j < THREADS; ++j)
            sum += smf[j * NSEG * 4 + pair];
        unsafeAtomicAdd(&acc[(size_t)b * NSEG * 4 + pair], sum);
    }
}

__global__ __launch_bounds__(BATCH * NSEG) void ovl_finalize(
    const float* __restrict__ acc,   // [B*S, 4]
    float* __restrict__ out)         // scalar
{
    const int tid = threadIdx.x;     // 0..511, one per global segment id
    const float cnt = acc[tid * 4 + 0];
    const float su  = acc[tid * 4 + 1];
    const float sv  = acc[tid * 4 + 2];
    const float s2  = acc[tid * 4 + 3];

    const bool is_bg = (tid & (NSEG - 1)) == 0;
    const bool valid = (cnt >= MIN_PIX) && !is_bg;

    const float safe_cnt = fmaxf(cnt, 1.0f);
    const float denom = fmaxf(cnt - 1.0f, 1.0f);
    const float var_sum = (s2 - (su * su + sv * sv) / safe_cnt) / denom;

    float t = valid ? var_sum : 0.0f;
    float n = valid ? 1.0f : 0.0f;

    // wave (64-lane) shuffle reduction
    #pragma unroll
    for (int off = 32; off >= 1; off >>= 1) {
        t += __shfl_down(t, off, 64);
        n += __shfl_down(n, off, 64);
    }

    __shared__ float st[8], sn[8];   // 512 threads = 8 waves
    const int wave = tid >> 6;
    const int lane = tid & 63;
    if (lane == 0) { st[wave] = t; sn[wave] = n; }
    __syncthreads();

    if (tid == 0) {
        float tot = 0.0f, ntot = 0.0f;
        #pragma unroll
        for (int w = 0; w < 8; ++w) { tot += st[w]; ntot += sn[w]; }
        out[0] = (ntot > 0.0f) ? (tot / fmaxf(ntot, 1.0f)) : 0.0f;
    }
}

extern "C" void kernel_launch(void* const* d_in, const int* in_sizes, int n_in,
                              void* d_out, int out_size, void* d_ws, size_t ws_size,
                              hipStream_t stream) {
    const float* flow = (const float*)d_in[0];
    const int* masks  = (const int*)d_in[1];
    float* out = (float*)d_out;
    float* acc = (float*)d_ws;

    hipMemsetAsync(acc, 0, ACC_FLOATS * sizeof(float), stream);

    dim3 grid(CHUNKS, BATCH);
    ovl_accum<<<grid, THREADS, 0, stream>>>(flow, masks, acc);
    ovl_finalize<<<1, BATCH * NSEG, 0, stream>>>(acc, out);
}